// Round 3
// baseline (876.285 us; speedup 1.0000x reference)
//
#include <hip/hip_runtime.h>
#include <stdint.h>

#define NQ 4096
#define NCAM 6
#define NV 22050
#define M_TOTAL (NCAM * NV) /* 132300 */

typedef __bf16 bf16x8 __attribute__((ext_vector_type(8)));
typedef float f32x4 __attribute__((ext_vector_type(4)));
typedef unsigned int u32x4 __attribute__((ext_vector_type(4)));

__device__ __forceinline__ unsigned short f2bf(float f) {
    union { float f; uint32_t u; } v; v.f = f;
    uint32_t u = v.u;
    uint32_t r = (u + 0x7FFFu + ((u >> 16) & 1u)) >> 16;
    return (unsigned short)r;
}
__device__ __forceinline__ float bf_lo(uint32_t u) {
    union { uint32_t u; float f; } v; v.u = u << 16; return v.f;
}
__device__ __forceinline__ float bf_hi(uint32_t u) {
    union { uint32_t u; float f; } v; v.u = u & 0xFFFF0000u; return v.f;
}
__device__ __forceinline__ int imin(int a, int b) { return a < b ? a : b; }
__device__ __forceinline__ int imax(int a, int b) { return a > b ? a : b; }

// ---------------- Wv transpose + bf16 convert (tiny) ----------------
__global__ void wvt_kernel(const float* __restrict__ Wv, unsigned short* __restrict__ WvT) {
    int n = blockIdx.x, k = threadIdx.x;
    WvT[n * 256 + k] = f2bf(Wv[k * 256 + n]);
}

// ---------------- value projection GEMM: val = value @ Wv + bv (bf16 MFMA) ----------------
__global__ __launch_bounds__(256) void val_gemm(const float* __restrict__ A,
                                                const unsigned short* __restrict__ BT,
                                                const float* __restrict__ bv,
                                                unsigned short* __restrict__ C) {
    __shared__ unsigned char Asm[64 * 80];   // 64 rows x 32 k bf16, row stride 80B (pad)
    __shared__ unsigned char Bsm[256 * 80];  // 256 n x 32 k bf16, row stride 80B
    const int t = threadIdx.x;
    const int wave = t >> 6, lane = t & 63;
    const int m_base = blockIdx.x * 64;

    f32x4 acc[4][4];
#pragma unroll
    for (int i = 0; i < 4; ++i)
#pragma unroll
        for (int j = 0; j < 4; ++j) acc[i][j] = (f32x4)0.0f;

    const int rsel = lane & 15, g = lane >> 4;

    for (int k0 = 0; k0 < 256; k0 += 32) {
        __syncthreads();
#pragma unroll
        for (int it = 0; it < 2; ++it) {
            int cc = t + it * 256;
            int r = cc >> 3, ck = cc & 7;
            int gr = imin(m_base + r, M_TOTAL - 1);
            float4 v = *reinterpret_cast<const float4*>(A + (size_t)gr * 256 + k0 + ck * 4);
            uint2 pk;
            pk.x = (uint32_t)f2bf(v.x) | ((uint32_t)f2bf(v.y) << 16);
            pk.y = (uint32_t)f2bf(v.z) | ((uint32_t)f2bf(v.w) << 16);
            *reinterpret_cast<uint2*>(&Asm[r * 80 + ck * 8]) = pk;
        }
#pragma unroll
        for (int it = 0; it < 4; ++it) {
            int cc = t + it * 256;
            int n = cc >> 2, ck = cc & 3;
            u32x4 v = *reinterpret_cast<const u32x4*>(BT + n * 256 + k0 + ck * 8);
            *reinterpret_cast<u32x4*>(&Bsm[n * 80 + ck * 16]) = v;
        }
        __syncthreads();

        bf16x8 af[4], bfr[4];
#pragma unroll
        for (int mi = 0; mi < 4; ++mi)
            af[mi] = __builtin_bit_cast(bf16x8,
                *reinterpret_cast<const u32x4*>(&Asm[(mi * 16 + rsel) * 80 + g * 16]));
#pragma unroll
        for (int ni = 0; ni < 4; ++ni)
            bfr[ni] = __builtin_bit_cast(bf16x8,
                *reinterpret_cast<const u32x4*>(&Bsm[(wave * 64 + ni * 16 + rsel) * 80 + g * 16]));
#pragma unroll
        for (int mi = 0; mi < 4; ++mi)
#pragma unroll
            for (int ni = 0; ni < 4; ++ni)
                acc[mi][ni] = __builtin_amdgcn_mfma_f32_16x16x32_bf16(af[mi], bfr[ni], acc[mi][ni], 0, 0, 0);
    }

#pragma unroll
    for (int ni = 0; ni < 4; ++ni) {
        int n = wave * 64 + ni * 16 + rsel;
        float bvv = bv[n];
#pragma unroll
        for (int mi = 0; mi < 4; ++mi)
#pragma unroll
            for (int j = 0; j < 4; ++j) {
                int m = m_base + mi * 16 + g * 4 + j;
                if (m < M_TOTAL) C[(size_t)m * 256 + n] = f2bf(acc[mi][ni][j] + bvv);
            }
    }
}

// ---------------- offsets + attention weights (q-only, cam-independent) ----------------
__global__ __launch_bounds__(256) void proj_kernel(const float* __restrict__ query,
                                                   const float* __restrict__ qpos,
                                                   const float* __restrict__ Ws,
                                                   const float* __restrict__ b_off,
                                                   const float* __restrict__ Wa,
                                                   const float* __restrict__ ba,
                                                   float* __restrict__ off_ws,
                                                   float* __restrict__ aw_ws) {
    __shared__ float qrow[4][256];
    __shared__ float logits[4][192];
    const int t = threadIdx.x;
    const int qb = blockIdx.x * 4;
#pragma unroll
    for (int j = 0; j < 4; ++j)
        qrow[j][t] = query[(size_t)(qb + j) * 256 + t] + qpos[(size_t)(qb + j) * 256 + t];
    __syncthreads();

    const float invn[3][2] = {{1.f / 168.f, 1.f / 100.f},
                              {1.f / 84.f, 1.f / 50.f},
                              {1.f / 42.f, 1.f / 25.f}};
#pragma unroll
    for (int pass = 0; pass < 3; ++pass) {
        int u = t + pass * 256;
        if (u < 384) {
            float a0 = 0.f, a1 = 0.f, a2 = 0.f, a3 = 0.f;
            for (int k = 0; k < 256; ++k) {
                float w = Ws[k * 384 + u];
                a0 += qrow[0][k] * w; a1 += qrow[1][k] * w;
                a2 += qrow[2][k] * w; a3 += qrow[3][k] * w;
            }
            int lp = u >> 1;               // (h*3+l)*8+p
            int l = (lp >> 3) % 3;
            float inv = invn[l][u & 1];
            float b = b_off[u];
            off_ws[(size_t)(qb + 0) * 384 + u] = (a0 + b) * inv;
            off_ws[(size_t)(qb + 1) * 384 + u] = (a1 + b) * inv;
            off_ws[(size_t)(qb + 2) * 384 + u] = (a2 + b) * inv;
            off_ws[(size_t)(qb + 3) * 384 + u] = (a3 + b) * inv;
        } else if (u < 576) {
            int u2 = u - 384;
            float a0 = 0.f, a1 = 0.f, a2 = 0.f, a3 = 0.f;
            for (int k = 0; k < 256; ++k) {
                float w = Wa[k * 192 + u2];
                a0 += qrow[0][k] * w; a1 += qrow[1][k] * w;
                a2 += qrow[2][k] * w; a3 += qrow[3][k] * w;
            }
            float b = ba[u2];
            logits[0][u2] = a0 + b; logits[1][u2] = a1 + b;
            logits[2][u2] = a2 + b; logits[3][u2] = a3 + b;
        }
    }
    __syncthreads();
    if (t < 32) {
        int jq = t >> 3, h = t & 7;
        float mx = -1e30f;
#pragma unroll
        for (int i = 0; i < 24; ++i) mx = fmaxf(mx, logits[jq][h * 24 + i]);
        float e[24];
        float s = 0.f;
#pragma unroll
        for (int i = 0; i < 24; ++i) { e[i] = __expf(logits[jq][h * 24 + i] - mx); s += e[i]; }
        float inv = 1.0f / s;
#pragma unroll
        for (int i = 0; i < 24; ++i)
            aw_ws[((size_t)(qb + jq) * 8 + h) * 24 + i] = e[i] * inv;
    }
}

// ---------------- bilinear sampling: 32 lanes per (q,c), 8 channels per lane ----------------
// XCD-affinity swizzle: 3072 blocks = 8 XCDs x 384; each XCD gets a contiguous pair
// range (<= 2 cameras, contiguous BEV patch) so the hot image region stays in its L2.
// Point loop in batches of 4: 16 dwordx4 loads in flight per batch.
__global__ __launch_bounds__(256, 4) void sample_kernel(const unsigned short* __restrict__ val,
                                                        const float* __restrict__ rpc,
                                                        const float* __restrict__ off_ws,
                                                        const float* __restrict__ aw_ws,
                                                        unsigned short* __restrict__ out_cam) {
    const int t = threadIdx.x;
    const int grp = t >> 5;             // 8 (q,c) pairs per block
    const int lane = t & 31;
    const int h = lane >> 2;            // head
    const int sub = lane & 3;           // channel quad within head
    int blk = blockIdx.x;
    int blk2 = (blk & 7) * 384 + (blk >> 3);   // bijective: 3072 = 8*384
    const int pair = blk2 * 8 + grp;           // pair = c*NQ + q
    const int c = pair >> 12;
    const int q = pair & (NQ - 1);

    float refx[4], refy[4];
    const float* rp = rpc + (size_t)pair * 8;
#pragma unroll
    for (int a = 0; a < 4; ++a) { refx[a] = rp[2 * a]; refy[a] = rp[2 * a + 1]; }

    const int chb = h * 32 + sub * 8;
    const unsigned short* vbase = val + (size_t)c * NV * 256 + chb;
    const float* offp = off_ws + (size_t)q * 384 + h * 48;   // [l][p][2]
    const float* awp = aw_ws + ((size_t)q * 8 + h) * 24;

    float acc[8];
#pragma unroll
    for (int i = 0; i < 8; ++i) acc[i] = 0.f;

    const int lw[3] = {168, 84, 42};
    const int lhh[3] = {100, 50, 25};
    const int lst[3] = {0, 16800, 21000};

#pragma unroll
    for (int l = 0; l < 3; ++l) {
        const int w = lw[l], hh = lhh[l];
        const float wf = (float)w, hf = (float)hh;
        const unsigned short* vlev = vbase + (size_t)lst[l] * 256;
#pragma unroll
        for (int b = 0; b < 2; ++b) {
            float W00[4], W10[4], W01[4], W11[4];
            int o00[4], o10[4], o01[4], o11[4];
#pragma unroll
            for (int i = 0; i < 4; ++i) {
                const int p = b * 4 + i;
                const int a = p & 3;
                float ox = offp[(l * 8 + p) * 2 + 0];
                float oy = offp[(l * 8 + p) * 2 + 1];
                float x = fmaf(refx[a] + ox, wf, -0.5f);
                float y = fmaf(refy[a] + oy, hf, -0.5f);
                float xf = floorf(x), yf = floorf(y);
                float lx = x - xf, ly = y - yf;
                int x0 = (int)xf, y0 = (int)yf;
                float aww = awp[l * 8 + p];

                float wx0 = (x0 >= 0 && x0 < w) ? (1.f - lx) : 0.f;
                float wx1 = (x0 >= -1 && x0 < w - 1) ? lx : 0.f;
                float wy0 = ((y0 >= 0 && y0 < hh) ? (1.f - ly) : 0.f) * aww;
                float wy1 = ((y0 >= -1 && y0 < hh - 1) ? ly : 0.f) * aww;

                int x0c = imin(imax(x0, 0), w - 1);
                int x1c = imin(imax(x0 + 1, 0), w - 1);
                int y0c = imin(imax(y0, 0), hh - 1);
                int y1c = imin(imax(y0 + 1, 0), hh - 1);
                int r0 = y0c * w, r1 = y1c * w;
                o00[i] = (r0 + x0c) * 256; o10[i] = (r0 + x1c) * 256;
                o01[i] = (r1 + x0c) * 256; o11[i] = (r1 + x1c) * 256;
                W00[i] = wx0 * wy0; W10[i] = wx1 * wy0;
                W01[i] = wx0 * wy1; W11[i] = wx1 * wy1;
            }
            u32x4 u00[4], u10[4], u01[4], u11[4];
#pragma unroll
            for (int i = 0; i < 4; ++i) {
                u00[i] = *reinterpret_cast<const u32x4*>(vlev + o00[i]);
                u10[i] = *reinterpret_cast<const u32x4*>(vlev + o10[i]);
                u01[i] = *reinterpret_cast<const u32x4*>(vlev + o01[i]);
                u11[i] = *reinterpret_cast<const u32x4*>(vlev + o11[i]);
            }
#pragma unroll
            for (int i = 0; i < 4; ++i) {
#pragma unroll
                for (int j = 0; j < 4; ++j) {
                    acc[2 * j] += W00[i] * bf_lo(u00[i][j]) + W10[i] * bf_lo(u10[i][j]) +
                                  W01[i] * bf_lo(u01[i][j]) + W11[i] * bf_lo(u11[i][j]);
                    acc[2 * j + 1] += W00[i] * bf_hi(u00[i][j]) + W10[i] * bf_hi(u10[i][j]) +
                                      W01[i] * bf_hi(u01[i][j]) + W11[i] * bf_hi(u11[i][j]);
                }
            }
        }
    }

    u32x4 o;
#pragma unroll
    for (int i = 0; i < 4; ++i)
        o[i] = (uint32_t)f2bf(acc[2 * i]) | ((uint32_t)f2bf(acc[2 * i + 1]) << 16);
    *reinterpret_cast<u32x4*>(out_cam + (size_t)pair * 256 + chb) = o;
}

// ---------------- mask-combine over cams + output projection + residual ----------------
__global__ __launch_bounds__(256) void combine_kernel(const unsigned short* __restrict__ out_cam,
                                                      const unsigned char* __restrict__ bev_mask,
                                                      const float* __restrict__ Wo,
                                                      const float* __restrict__ bo,
                                                      const float* __restrict__ query,
                                                      float* __restrict__ out) {
    __shared__ float s_lds[8][256];
    __shared__ unsigned int hitm[8];
    __shared__ float invc[8];
    const int t = threadIdx.x;
    const int qb = blockIdx.x * 8;

    if (t < 8) {
        int q = qb + t;
        unsigned int m = 0;
        int cnt = 0;
        for (int c = 0; c < 6; ++c) {
            const unsigned char* bm = bev_mask + ((size_t)c * NQ + q) * 4;
            if (bm[0] | bm[1] | bm[2] | bm[3]) { m |= (1u << c); cnt++; }
        }
        hitm[t] = m;
        invc[t] = 1.0f / (float)imax(cnt, 1);
    }
    __syncthreads();
#pragma unroll
    for (int j = 0; j < 8; ++j) {
        unsigned int m = hitm[j];
        float ic = invc[j];
        float s = 0.f;
#pragma unroll
        for (int c = 0; c < 6; ++c)
            if ((m >> c) & 1u) {
                unsigned short u = out_cam[((size_t)c * NQ + qb + j) * 256 + t];
                union { uint32_t u; float f; } v; v.u = ((uint32_t)u) << 16;
                s += v.f;
            }
        s_lds[j][t] = s * ic;
    }
    __syncthreads();
    float acc[8] = {0.f, 0.f, 0.f, 0.f, 0.f, 0.f, 0.f, 0.f};
    for (int k = 0; k < 256; ++k) {
        float wv = Wo[k * 256 + t];
#pragma unroll
        for (int j = 0; j < 8; ++j) acc[j] += s_lds[j][k] * wv;
    }
    float bb = bo[t];
#pragma unroll
    for (int j = 0; j < 8; ++j)
        out[(size_t)(qb + j) * 256 + t] = acc[j] + bb + query[(size_t)(qb + j) * 256 + t];
}

extern "C" void kernel_launch(void* const* d_in, const int* in_sizes, int n_in,
                              void* d_out, int out_size, void* d_ws, size_t ws_size,
                              hipStream_t stream) {
    const float* query = (const float*)d_in[0];
    const float* value = (const float*)d_in[2];
    const float* qpos = (const float*)d_in[3];
    const float* rpc = (const float*)d_in[4];
    const unsigned char* bev = (const unsigned char*)d_in[5];
    const float* Wv = (const float*)d_in[8];
    const float* bv = (const float*)d_in[9];
    const float* Ws = (const float*)d_in[10];
    const float* b_off = (const float*)d_in[11];
    const float* Wa = (const float*)d_in[12];
    const float* ba = (const float*)d_in[13];
    const float* Wo = (const float*)d_in[14];
    const float* bo = (const float*)d_in[15];
    float* out = (float*)d_out;

    char* ws = (char*)d_ws;
    unsigned short* val_ws = (unsigned short*)ws;                        // 67,737,600 B
    size_t o = 67737600;
    float* off_ws = (float*)(ws + o);            o += 6291456;           // 4096*384*4
    float* aw_ws = (float*)(ws + o);             o += 3145728;           // 4096*192*4
    unsigned short* out_cam = (unsigned short*)(ws + o); o += 12582912;  // 6*4096*256*2
    unsigned short* WvT = (unsigned short*)(ws + o);                     // 131,072 B

    wvt_kernel<<<256, 256, 0, stream>>>(Wv, WvT);
    proj_kernel<<<NQ / 4, 256, 0, stream>>>(query, qpos, Ws, b_off, Wa, ba, off_ws, aw_ws);
    val_gemm<<<(M_TOTAL + 63) / 64, 256, 0, stream>>>(value, WvT, bv, val_ws);
    sample_kernel<<<(NQ * NCAM) / 8, 256, 0, stream>>>(val_ws, rpc, off_ws, aw_ws, out_cam);
    combine_kernel<<<NQ / 8, 256, 0, stream>>>(out_cam, bev, Wo, bo, query, out);
}

// Round 4
// 223.145 us; speedup vs baseline: 3.9270x; 3.9270x over previous
//
#include <hip/hip_runtime.h>
#include <stdint.h>

#define NQ 4096
#define NCAM 6
#define NV 22050
#define M_TOTAL (NCAM * NV) /* 132300 */

typedef __bf16 bf16x8 __attribute__((ext_vector_type(8)));
typedef float f32x4 __attribute__((ext_vector_type(4)));
typedef unsigned int u32x4 __attribute__((ext_vector_type(4)));

__device__ __forceinline__ unsigned short f2bf(float f) {
    union { float f; uint32_t u; } v; v.f = f;
    uint32_t u = v.u;
    uint32_t r = (u + 0x7FFFu + ((u >> 16) & 1u)) >> 16;
    return (unsigned short)r;
}
__device__ __forceinline__ float bf_lo(uint32_t u) {
    union { uint32_t u; float f; } v; v.u = u << 16; return v.f;
}
__device__ __forceinline__ float bf_hi(uint32_t u) {
    union { uint32_t u; float f; } v; v.u = u & 0xFFFF0000u; return v.f;
}
__device__ __forceinline__ int imin(int a, int b) { return a < b ? a : b; }
__device__ __forceinline__ int imax(int a, int b) { return a > b ? a : b; }

// ---------------- Wv transpose + bf16 convert (tiny) ----------------
__global__ void wvt_kernel(const float* __restrict__ Wv, unsigned short* __restrict__ WvT) {
    int n = blockIdx.x, k = threadIdx.x;
    WvT[n * 256 + k] = f2bf(Wv[k * 256 + n]);
}

// ---------------- value projection GEMM: val = value @ Wv + bv (bf16 MFMA) ----------------
// Output layout: val2[c][h][pix][32ch]  (per-(cam,head) planes, 1.41 MB each)
__global__ __launch_bounds__(256) void val_gemm(const float* __restrict__ A,
                                                const unsigned short* __restrict__ BT,
                                                const float* __restrict__ bv,
                                                unsigned short* __restrict__ C) {
    __shared__ unsigned char Asm[64 * 80];   // 64 rows x 32 k bf16, row stride 80B (pad)
    __shared__ unsigned char Bsm[256 * 80];  // 256 n x 32 k bf16, row stride 80B
    const int t = threadIdx.x;
    const int wave = t >> 6, lane = t & 63;
    const int m_base = blockIdx.x * 64;

    f32x4 acc[4][4];
#pragma unroll
    for (int i = 0; i < 4; ++i)
#pragma unroll
        for (int j = 0; j < 4; ++j) acc[i][j] = (f32x4)0.0f;

    const int rsel = lane & 15, g = lane >> 4;

    for (int k0 = 0; k0 < 256; k0 += 32) {
        __syncthreads();
#pragma unroll
        for (int it = 0; it < 2; ++it) {
            int cc = t + it * 256;
            int r = cc >> 3, ck = cc & 7;
            int gr = imin(m_base + r, M_TOTAL - 1);
            float4 v = *reinterpret_cast<const float4*>(A + (size_t)gr * 256 + k0 + ck * 4);
            uint2 pk;
            pk.x = (uint32_t)f2bf(v.x) | ((uint32_t)f2bf(v.y) << 16);
            pk.y = (uint32_t)f2bf(v.z) | ((uint32_t)f2bf(v.w) << 16);
            *reinterpret_cast<uint2*>(&Asm[r * 80 + ck * 8]) = pk;
        }
#pragma unroll
        for (int it = 0; it < 4; ++it) {
            int cc = t + it * 256;
            int n = cc >> 2, ck = cc & 3;
            u32x4 v = *reinterpret_cast<const u32x4*>(BT + n * 256 + k0 + ck * 8);
            *reinterpret_cast<u32x4*>(&Bsm[n * 80 + ck * 16]) = v;
        }
        __syncthreads();

        bf16x8 af[4], bfr[4];
#pragma unroll
        for (int mi = 0; mi < 4; ++mi)
            af[mi] = __builtin_bit_cast(bf16x8,
                *reinterpret_cast<const u32x4*>(&Asm[(mi * 16 + rsel) * 80 + g * 16]));
#pragma unroll
        for (int ni = 0; ni < 4; ++ni)
            bfr[ni] = __builtin_bit_cast(bf16x8,
                *reinterpret_cast<const u32x4*>(&Bsm[(wave * 64 + ni * 16 + rsel) * 80 + g * 16]));
#pragma unroll
        for (int mi = 0; mi < 4; ++mi)
#pragma unroll
            for (int ni = 0; ni < 4; ++ni)
                acc[mi][ni] = __builtin_amdgcn_mfma_f32_16x16x32_bf16(af[mi], bfr[ni], acc[mi][ni], 0, 0, 0);
    }

#pragma unroll
    for (int ni = 0; ni < 4; ++ni) {
        int n = wave * 64 + ni * 16 + rsel;
        float bvv = bv[n];
        const int hp = n >> 5, ch = n & 31;
#pragma unroll
        for (int mi = 0; mi < 4; ++mi)
#pragma unroll
            for (int j = 0; j < 4; ++j) {
                int m = m_base + mi * 16 + g * 4 + j;
                if (m < M_TOTAL) {
                    unsigned int um = (unsigned int)m;
                    unsigned int c = um / 22050u;
                    unsigned int pix = um - c * 22050u;
                    C[(((size_t)c * 8 + hp) * NV + pix) * 32 + ch] = f2bf(acc[mi][ni][j] + bvv);
                }
            }
    }
}

// ---------------- offsets + attention weights (q-only, cam-independent) ----------------
__global__ __launch_bounds__(256) void proj_kernel(const float* __restrict__ query,
                                                   const float* __restrict__ qpos,
                                                   const float* __restrict__ Ws,
                                                   const float* __restrict__ b_off,
                                                   const float* __restrict__ Wa,
                                                   const float* __restrict__ ba,
                                                   float* __restrict__ off_ws,
                                                   float* __restrict__ aw_ws) {
    __shared__ float qrow[4][256];
    __shared__ float logits[4][192];
    const int t = threadIdx.x;
    const int qb = blockIdx.x * 4;
#pragma unroll
    for (int j = 0; j < 4; ++j)
        qrow[j][t] = query[(size_t)(qb + j) * 256 + t] + qpos[(size_t)(qb + j) * 256 + t];
    __syncthreads();

    const float invn[3][2] = {{1.f / 168.f, 1.f / 100.f},
                              {1.f / 84.f, 1.f / 50.f},
                              {1.f / 42.f, 1.f / 25.f}};
#pragma unroll
    for (int pass = 0; pass < 3; ++pass) {
        int u = t + pass * 256;
        if (u < 384) {
            float a0 = 0.f, a1 = 0.f, a2 = 0.f, a3 = 0.f;
            for (int k = 0; k < 256; ++k) {
                float w = Ws[k * 384 + u];
                a0 += qrow[0][k] * w; a1 += qrow[1][k] * w;
                a2 += qrow[2][k] * w; a3 += qrow[3][k] * w;
            }
            int lp = u >> 1;               // (h*3+l)*8+p
            int l = (lp >> 3) % 3;
            float inv = invn[l][u & 1];
            float b = b_off[u];
            off_ws[(size_t)(qb + 0) * 384 + u] = (a0 + b) * inv;
            off_ws[(size_t)(qb + 1) * 384 + u] = (a1 + b) * inv;
            off_ws[(size_t)(qb + 2) * 384 + u] = (a2 + b) * inv;
            off_ws[(size_t)(qb + 3) * 384 + u] = (a3 + b) * inv;
        } else if (u < 576) {
            int u2 = u - 384;
            float a0 = 0.f, a1 = 0.f, a2 = 0.f, a3 = 0.f;
            for (int k = 0; k < 256; ++k) {
                float w = Wa[k * 192 + u2];
                a0 += qrow[0][k] * w; a1 += qrow[1][k] * w;
                a2 += qrow[2][k] * w; a3 += qrow[3][k] * w;
            }
            float b = ba[u2];
            logits[0][u2] = a0 + b; logits[1][u2] = a1 + b;
            logits[2][u2] = a2 + b; logits[3][u2] = a3 + b;
        }
    }
    __syncthreads();
    if (t < 32) {
        int jq = t >> 3, h = t & 7;
        float mx = -1e30f;
#pragma unroll
        for (int i = 0; i < 24; ++i) mx = fmaxf(mx, logits[jq][h * 24 + i]);
        float e[24];
        float s = 0.f;
#pragma unroll
        for (int i = 0; i < 24; ++i) { e[i] = __expf(logits[jq][h * 24 + i] - mx); s += e[i]; }
        float inv = 1.0f / s;
#pragma unroll
        for (int i = 0; i < 24; ++i)
            aw_ws[((size_t)(qb + jq) * 8 + h) * 24 + i] = e[i] * inv;
    }
}

// ---------------- bilinear sampling: one (cam,head) plane per block ----------------
// val layout [c][h][pix][32ch]; plane = 1.41 MB. Block = 64 q x 4 lanes (8 ch/lane).
// XCD swizzle: p = x + 8*s; XCD x drains its 6 plane-groups sequentially so the
// in-flight working set (~1.5 planes ~ 2-3 MB) fits the 4 MB per-XCD L2.
// Corner fetch = one 64 B aligned line per 4-lane quad.
__global__ __launch_bounds__(256) void sample_kernel(const unsigned short* __restrict__ val,
                                                     const float* __restrict__ rpc,
                                                     const float* __restrict__ off_ws,
                                                     const float* __restrict__ aw_ws,
                                                     unsigned short* __restrict__ out_cam) {
    const int t = threadIdx.x;
    const int qs = t >> 2;          // 64 q-slots per block
    const int sub = t & 3;          // channel quad within head
    const int p = blockIdx.x;       // 3072 blocks = 8 XCD x 6 groups x 64
    const int x = p & 7;
    const int g = x + 8 * (p >> 9);     // group = c*8 + h
    const int wblk = (p >> 3) & 63;
    const int c = g >> 3, h = g & 7;
    const int q = wblk * 64 + qs;
    const int pair = c * NQ + q;

    float refx[4], refy[4];
    const float* rp = rpc + (size_t)pair * 8;
#pragma unroll
    for (int a = 0; a < 4; ++a) { refx[a] = rp[2 * a]; refy[a] = rp[2 * a + 1]; }

    const unsigned short* vbase = val + (size_t)g * NV * 32 + sub * 8;
    const float* offp = off_ws + (size_t)q * 384 + h * 48;   // [l][p][2]
    const float* awp = aw_ws + ((size_t)q * 8 + h) * 24;

    float acc[8];
#pragma unroll
    for (int i = 0; i < 8; ++i) acc[i] = 0.f;

    const int lw[3] = {168, 84, 42};
    const int lhh[3] = {100, 50, 25};
    const int lst[3] = {0, 16800, 21000};

#pragma unroll
    for (int l = 0; l < 3; ++l) {
        const int w = lw[l], hh = lhh[l];
        const float wf = (float)w, hf = (float)hh;
        const unsigned short* vlev = vbase + (size_t)lst[l] * 32;
#pragma unroll
        for (int pt = 0; pt < 8; ++pt) {
            const int a = pt & 3;
            float ox = offp[(l * 8 + pt) * 2 + 0];
            float oy = offp[(l * 8 + pt) * 2 + 1];
            float xx = fmaf(refx[a] + ox, wf, -0.5f);
            float yy = fmaf(refy[a] + oy, hf, -0.5f);
            float xf = floorf(xx), yf = floorf(yy);
            float lx = xx - xf, ly = yy - yf;
            int x0 = (int)xf, y0 = (int)yf;
            float aww = awp[l * 8 + pt];

            float wx0 = (x0 >= 0 && x0 < w) ? (1.f - lx) : 0.f;
            float wx1 = (x0 >= -1 && x0 < w - 1) ? lx : 0.f;
            float wy0 = ((y0 >= 0 && y0 < hh) ? (1.f - ly) : 0.f) * aww;
            float wy1 = ((y0 >= -1 && y0 < hh - 1) ? ly : 0.f) * aww;

            int x0c = imin(imax(x0, 0), w - 1);
            int x1c = imin(imax(x0 + 1, 0), w - 1);
            int y0c = imin(imax(y0, 0), hh - 1);
            int y1c = imin(imax(y0 + 1, 0), hh - 1);

            int r0 = y0c * w, r1 = y1c * w;
            u32x4 u00 = *reinterpret_cast<const u32x4*>(vlev + (size_t)(r0 + x0c) * 32);
            u32x4 u10 = *reinterpret_cast<const u32x4*>(vlev + (size_t)(r0 + x1c) * 32);
            u32x4 u01 = *reinterpret_cast<const u32x4*>(vlev + (size_t)(r1 + x0c) * 32);
            u32x4 u11 = *reinterpret_cast<const u32x4*>(vlev + (size_t)(r1 + x1c) * 32);

            float w00 = wx0 * wy0, w10 = wx1 * wy0, w01 = wx0 * wy1, w11 = wx1 * wy1;
#pragma unroll
            for (int i = 0; i < 4; ++i) {
                acc[2 * i] += w00 * bf_lo(u00[i]) + w10 * bf_lo(u10[i]) +
                              w01 * bf_lo(u01[i]) + w11 * bf_lo(u11[i]);
                acc[2 * i + 1] += w00 * bf_hi(u00[i]) + w10 * bf_hi(u10[i]) +
                                  w01 * bf_hi(u01[i]) + w11 * bf_hi(u11[i]);
            }
        }
    }

    u32x4 o;
#pragma unroll
    for (int i = 0; i < 4; ++i)
        o[i] = (uint32_t)f2bf(acc[2 * i]) | ((uint32_t)f2bf(acc[2 * i + 1]) << 16);
    *reinterpret_cast<u32x4*>(out_cam + (size_t)pair * 256 + h * 32 + sub * 8) = o;
}

// ---------------- mask-combine over cams + output projection + residual ----------------
__global__ __launch_bounds__(256) void combine_kernel(const unsigned short* __restrict__ out_cam,
                                                      const unsigned char* __restrict__ bev_mask,
                                                      const float* __restrict__ Wo,
                                                      const float* __restrict__ bo,
                                                      const float* __restrict__ query,
                                                      float* __restrict__ out) {
    __shared__ float s_lds[8][256];
    __shared__ unsigned int hitm[8];
    __shared__ float invc[8];
    const int t = threadIdx.x;
    const int qb = blockIdx.x * 8;

    if (t < 8) {
        int q = qb + t;
        unsigned int m = 0;
        int cnt = 0;
        for (int c = 0; c < 6; ++c) {
            const unsigned char* bm = bev_mask + ((size_t)c * NQ + q) * 4;
            if (bm[0] | bm[1] | bm[2] | bm[3]) { m |= (1u << c); cnt++; }
        }
        hitm[t] = m;
        invc[t] = 1.0f / (float)imax(cnt, 1);
    }
    __syncthreads();
#pragma unroll
    for (int j = 0; j < 8; ++j) {
        unsigned int m = hitm[j];
        float ic = invc[j];
        float s = 0.f;
#pragma unroll
        for (int c = 0; c < 6; ++c)
            if ((m >> c) & 1u) {
                unsigned short u = out_cam[((size_t)c * NQ + qb + j) * 256 + t];
                union { uint32_t u; float f; } v; v.u = ((uint32_t)u) << 16;
                s += v.f;
            }
        s_lds[j][t] = s * ic;
    }
    __syncthreads();
    float acc[8] = {0.f, 0.f, 0.f, 0.f, 0.f, 0.f, 0.f, 0.f};
    for (int k = 0; k < 256; ++k) {
        float wv = Wo[k * 256 + t];
#pragma unroll
        for (int j = 0; j < 8; ++j) acc[j] += s_lds[j][k] * wv;
    }
    float bb = bo[t];
#pragma unroll
    for (int j = 0; j < 8; ++j)
        out[(size_t)(qb + j) * 256 + t] = acc[j] + bb + query[(size_t)(qb + j) * 256 + t];
}

extern "C" void kernel_launch(void* const* d_in, const int* in_sizes, int n_in,
                              void* d_out, int out_size, void* d_ws, size_t ws_size,
                              hipStream_t stream) {
    const float* query = (const float*)d_in[0];
    const float* value = (const float*)d_in[2];
    const float* qpos = (const float*)d_in[3];
    const float* rpc = (const float*)d_in[4];
    const unsigned char* bev = (const unsigned char*)d_in[5];
    const float* Wv = (const float*)d_in[8];
    const float* bv = (const float*)d_in[9];
    const float* Ws = (const float*)d_in[10];
    const float* b_off = (const float*)d_in[11];
    const float* Wa = (const float*)d_in[12];
    const float* ba = (const float*)d_in[13];
    const float* Wo = (const float*)d_in[14];
    const float* bo = (const float*)d_in[15];
    float* out = (float*)d_out;

    char* ws = (char*)d_ws;
    unsigned short* val_ws = (unsigned short*)ws;                        // 67,737,600 B
    size_t o = 67737600;
    float* off_ws = (float*)(ws + o);            o += 6291456;           // 4096*384*4
    float* aw_ws = (float*)(ws + o);             o += 3145728;           // 4096*192*4
    unsigned short* out_cam = (unsigned short*)(ws + o); o += 12582912;  // 6*4096*256*2
    unsigned short* WvT = (unsigned short*)(ws + o);                     // 131,072 B

    wvt_kernel<<<256, 256, 0, stream>>>(Wv, WvT);
    proj_kernel<<<NQ / 4, 256, 0, stream>>>(query, qpos, Ws, b_off, Wa, ba, off_ws, aw_ws);
    val_gemm<<<(M_TOTAL + 63) / 64, 256, 0, stream>>>(value, WvT, bv, val_ws);
    sample_kernel<<<3072, 256, 0, stream>>>(val_ws, rpc, off_ws, aw_ws, out_cam);
    combine_kernel<<<NQ / 8, 256, 0, stream>>>(out_cam, bev, Wo, bo, query, out);
}